// Round 2
// baseline (108.452 us; speedup 1.0000x reference)
//
#include <hip/hip_runtime.h>
#include <hip/hip_bf16.h>

// DiceActor fused forward, MI355X (gfx950).
// out layout (f32): action[B*32] | pretanh[B*32] | log_prob[B] | pretanh_log_prob[B]

#define B_TOTAL 262144
#define OBS_D   128
#define LAT     256
#define ACT     32

typedef __attribute__((ext_vector_type(8))) short bf16x8;   // 8 bf16 in 4 VGPRs
typedef __attribute__((ext_vector_type(4))) float f32x4;

__device__ __forceinline__ unsigned short f2bf(float x) {
  __hip_bfloat16 h = __float2bfloat16(x);
  return __builtin_bit_cast(unsigned short, h);
}

__device__ __forceinline__ float ftanh(float x) {
  float ax = fabsf(x);
  float e  = __expf(-2.f * ax);
  float y  = (1.f - e) / (1.f + e);
  return x < 0.f ? -y : y;
}

// ---------------------------------------------------------------------------
// Prep kernel: pack weights as bf16 into d_ws.
//  region A [0, 65536) bytes: W_bb as per-(wave,frag,lane) B-fragments:
//    elem = w*8192 + (t*4+s)*512 + lane*8 + j
//    value = bf16( W_bb[k = s*32 + (lane>>4)*8 + j][n = w*64 + t*16 + (lane&15)] )
//  region B [65536, 98304) bytes: head B-fragments for direct global loads:
//    elem = 32768 + ((s*4+u)*64 + lane)*8 + j
//    value = Wh[n = u*16 + (lane&15)][k = s*32 + (lane>>4)*8 + j]
//    where Wh[n][k]: n<32 -> Wmu[k][n], else Wsg[k][n-32]
// ---------------------------------------------------------------------------
__global__ void dice_prep(const float* __restrict__ Wbb,
                          const float* __restrict__ Wmu,
                          const float* __restrict__ Wsg,
                          unsigned short* __restrict__ wpack) {
  int tid = blockIdx.x * 256 + threadIdx.x;      // 192*256 = 49152 exactly
  if (tid < 32768) {
    int w    = tid >> 13;
    int rem  = tid & 8191;
    int f    = rem >> 9;
    int lane = (rem >> 3) & 63;
    int j    = rem & 7;
    int t = f >> 2, s = f & 3;
    int k = s * 32 + (lane >> 4) * 8 + j;
    int n = w * 64 + t * 16 + (lane & 15);
    wpack[tid] = f2bf(Wbb[k * LAT + n]);
  } else {
    int i    = tid - 32768;                      // [0, 16384)
    int f    = i >> 9;                           // frag 0..31 = s*4+u
    int lane = (i >> 3) & 63;
    int j    = i & 7;
    int s = f >> 2, u = f & 3;
    int n = u * 16 + (lane & 15);
    int k = s * 32 + (lane >> 4) * 8 + j;
    float v = (n < 32) ? Wmu[k * ACT + n] : Wsg[k * ACT + (n - 32)];
    wpack[32768 + i] = f2bf(v);
  }
}

// ---------------------------------------------------------------------------
// Main kernel: 256 threads (4 waves), 64 rows per block, grid 4096.
// Wave w owns latent cols [64w, 64w+64) in the backbone (W_bb frags in regs).
// LDS = 8K (obs half) + 32K (h) = 40960 B -> 4 blocks/CU, 16 waves/CU.
// ---------------------------------------------------------------------------
__global__ __launch_bounds__(256, 4) void dice_main(
    const float* __restrict__ obs, const float* __restrict__ noise,
    const unsigned short* __restrict__ wpack,
    const float* __restrict__ b_bb, const float* __restrict__ b_mu,
    const float* __restrict__ b_sg, float* __restrict__ out) {

  __shared__ __align__(16) unsigned char s_obs[8192];   // 32 rows x 128 bf16, swizzled
  __shared__ __align__(16) unsigned char s_h[32768];    // 64 rows x 256 bf16, swizzled

  const int tid  = threadIdx.x;
  const int wave = tid >> 6, lane = tid & 63;
  const int lrow = lane & 15, lgrp = lane >> 4;
  const int blockRow0 = blockIdx.x * 64;

  // ---- noise prefetch (overlaps the whole GEMM pipeline) ----
  float nse0[4], nse1[4];
#pragma unroll
  for (int r = 0; r < 4; ++r) {
    int row = blockRow0 + wave * 16 + lgrp * 4 + r;
    nse0[r] = noise[row * ACT + lrow];
    nse1[r] = noise[row * ACT + lrow + 16];
  }

  // ---- W_bb fragments -> registers (coalesced 16B/lane, L2-hot) ----
  bf16x8 wf[16];
  {
    const bf16x8* wp = (const bf16x8*)wpack + wave * 1024 + lane;
#pragma unroll
    for (int f = 0; f < 16; ++f) wf[f] = wp[f * 64];
  }

  // backbone bias per owned col
  float bbias[4];
#pragma unroll
  for (int t = 0; t < 4; ++t) bbias[t] = b_bb[wave * 64 + t * 16 + lrow];

  // ---- stage obs half (32 rows) into s_obs, f32 -> bf16, swizzled ----
  auto stage_obs = [&](int half) {
    const float4* op = (const float4*)obs + (size_t)(blockRow0 + half * 32) * 32;
#pragma unroll
    for (int i = 0; i < 4; ++i) {
      int flat = i * 256 + tid;
      int m = flat >> 5, kq = flat & 31;           // m: local row, kq: float4 idx in row
      float4 v = op[m * 32 + kq];
      unsigned int lo = (unsigned int)f2bf(v.x) | ((unsigned int)f2bf(v.y) << 16);
      unsigned int hi = (unsigned int)f2bf(v.z) | ((unsigned int)f2bf(v.w) << 16);
      int byte = m * 256 + ((kq * 8) ^ ((m & 15) << 4));
      *(uint2*)(s_obs + byte) = make_uint2(lo, hi);
    }
  };

  // ---- backbone for one 16-row strip: h[m0..m0+16)[wave cols] ----
  auto backbone = [&](int st) {
    const int m0 = st * 16, mloc = (st & 1) * 16;
    bf16x8 a[4];
#pragma unroll
    for (int s = 0; s < 4; ++s) {
      int abyte = (mloc + lrow) * 256 + ((s * 64 + lgrp * 16) ^ (lrow << 4));
      a[s] = *(const bf16x8*)(s_obs + abyte);
    }
    f32x4 acc[4];
#pragma unroll
    for (int t = 0; t < 4; ++t) acc[t] = (f32x4)(0.f);
#pragma unroll
    for (int t = 0; t < 4; ++t)
#pragma unroll
      for (int s = 0; s < 4; ++s)
        acc[t] = __builtin_amdgcn_mfma_f32_16x16x32_bf16(a[s], wf[t * 4 + s], acc[t], 0, 0, 0);
    // bias + relu + bf16 -> s_h (swizzled)
#pragma unroll
    for (int t = 0; t < 4; ++t) {
      int col = wave * 64 + t * 16 + lrow;
#pragma unroll
      for (int r = 0; r < 4; ++r) {
        int row = m0 + lgrp * 4 + r;
        float v = fmaxf(acc[t][r] + bbias[t], 0.f);
        int byte = row * 512 + ((2 * col) ^ ((row & 15) << 4));
        *(unsigned short*)(s_h + byte) = f2bf(v);
      }
    }
  };

  stage_obs(0);
  __syncthreads();
  backbone(0);
  backbone(1);
  __syncthreads();
  stage_obs(1);
  __syncthreads();
  backbone(2);
  backbone(3);
  __syncthreads();

  // ---- head GEMM: rows [wave*16, wave*16+16), cols mu(0-31) | logstd(0-31) ----
  // B-fragments streamed straight from global (32 KB table, L2/L1-hot).
  const bf16x8* hb = (const bf16x8*)(wpack + 32768);
  f32x4 acc2[4];
#pragma unroll
  for (int u = 0; u < 4; ++u) acc2[u] = (f32x4)(0.f);
#pragma unroll
  for (int s = 0; s < 8; ++s) {
    int off = (s * 64 + lgrp * 16) ^ (lrow << 4);
    bf16x8 a = *(const bf16x8*)(s_h + (wave * 16 + lrow) * 512 + off);
#pragma unroll
    for (int u = 0; u < 4; ++u) {
      bf16x8 b = hb[(s * 4 + u) * 64 + lane];
      acc2[u] = __builtin_amdgcn_mfma_f32_16x16x32_bf16(a, b, acc2[u], 0, 0, 0);
    }
  }

  // ---- epilogue ----
  const float bmu0 = b_mu[lrow], bmu1 = b_mu[lrow + 16];
  const float bsg0 = b_sg[lrow], bsg1 = b_sg[lrow + 16];
  float* out_act = out;
  float* out_pre = out + (B_TOTAL * ACT);
  float* out_lp  = out + (2 * B_TOTAL * ACT);
  float* out_plp = out_lp + B_TOTAL;

  float s1v[4], s2v[4];
#pragma unroll
  for (int r = 0; r < 4; ++r) {
    int row = blockRow0 + wave * 16 + lgrp * 4 + r;
    float mu0 = fminf(fmaxf(acc2[0][r] + bmu0, -7.f), 7.f);
    float mu1 = fminf(fmaxf(acc2[1][r] + bmu1, -7.f), 7.f);
    float ls0 = fminf(fmaxf(acc2[2][r] + bsg0, -2.f), 5.f);
    float ls1 = fminf(fmaxf(acc2[3][r] + bsg1, -2.f), 5.f);
    float sp0 = __expf(0.5f * ls0), sp1 = __expf(0.5f * ls1);
    float p0 = fmaf(sp0, nse0[r], mu0), p1 = fmaf(sp1, nse1[r], mu1);
    float a0 = ftanh(p0), a1 = ftanh(p1);
    float d0 = p0 - mu0, d1 = p1 - mu1;
    float t1 = fmaf(d0 * d0, __expf(-ls0), ls0) + fmaf(d1 * d1, __expf(-ls1), ls1);
    float t2 = __logf(1.f - a0 * a0 + 1e-6f) + __logf(1.f - a1 * a1 + 1e-6f);
    out_act[row * ACT + lrow]      = a0;
    out_act[row * ACT + lrow + 16] = a1;
    out_pre[row * ACT + lrow]      = p0;
    out_pre[row * ACT + lrow + 16] = p1;
    s1v[r] = t1;
    s2v[r] = t2;
  }
  // 16-lane butterfly: every lane in a 16-group ends with full row sums
#pragma unroll
  for (int m = 1; m < 16; m <<= 1) {
#pragma unroll
    for (int r = 0; r < 4; ++r) {
      s1v[r] += __shfl_xor(s1v[r], m, 64);
      s2v[r] += __shfl_xor(s2v[r], m, 64);
    }
  }
  if (lrow < 4) {
    int r = lrow;
    float s1 = (r == 0) ? s1v[0] : (r == 1) ? s1v[1] : (r == 2) ? s1v[2] : s1v[3];
    float s2 = (r == 0) ? s2v[0] : (r == 1) ? s2v[1] : (r == 2) ? s2v[2] : s2v[3];
    int row = blockRow0 + wave * 16 + lgrp * 4 + r;
    float plp = -0.5f * s1 - 29.406033062549525f;   // 0.5*32*log(2*pi)
    out_plp[row] = plp;
    out_lp[row]  = plp - s2;
  }
}

extern "C" void kernel_launch(void* const* d_in, const int* in_sizes, int n_in,
                              void* d_out, int out_size, void* d_ws, size_t ws_size,
                              hipStream_t stream) {
  const float* obs = (const float*)d_in[0];
  const float* noi = (const float*)d_in[1];
  const float* Wbb = (const float*)d_in[2];
  const float* bbb = (const float*)d_in[3];
  const float* Wmu = (const float*)d_in[4];
  const float* bmu = (const float*)d_in[5];
  const float* Wsg = (const float*)d_in[6];
  const float* bsg = (const float*)d_in[7];
  unsigned short* wpack = (unsigned short*)d_ws;   // needs 98304 bytes

  hipLaunchKernelGGL(dice_prep, dim3(192), dim3(256), 0, stream, Wbb, Wmu, Wsg, wpack);
  hipLaunchKernelGGL(dice_main, dim3(B_TOTAL / 64), dim3(256), 0, stream,
                     obs, noi, wpack, bbb, bmu, bsg, (float*)d_out);
}

// Round 3
// 63.777 us; speedup vs baseline: 1.7005x; 1.7005x over previous
//
#include <hip/hip_runtime.h>
#include <hip/hip_bf16.h>

// DiceActor fused forward, MI355X (gfx950).
// out layout (f32): action[B*32] | pretanh[B*32] | log_prob[B] | pretanh_log_prob[B]

#define B_TOTAL 262144
#define OBS_D   128
#define LAT     256
#define ACT     32

typedef __attribute__((ext_vector_type(8))) short bf16x8;   // 8 bf16 in 4 VGPRs
typedef __attribute__((ext_vector_type(4))) float f32x4;

__device__ __forceinline__ unsigned short f2bf(float x) {
  __hip_bfloat16 h = __float2bfloat16(x);
  return __builtin_bit_cast(unsigned short, h);
}

__device__ __forceinline__ float ftanh(float x) {
  float ax = fabsf(x);
  float e  = __expf(-2.f * ax);
  float y  = (1.f - e) / (1.f + e);
  return x < 0.f ? -y : y;
}

// ---------------------------------------------------------------------------
// Prep kernel: pack weights as bf16 into d_ws.
//  region A [0, 65536) bytes: W_bb as per-(wave,frag,lane) B-fragments:
//    elem = w*8192 + (t*4+s)*512 + lane*8 + j
//    value = bf16( W_bb[k = s*32 + (lane>>4)*8 + j][n = w*64 + t*16 + (lane&15)] )
//  region B [65536, 98304) bytes: head B-fragments for direct global loads:
//    elem = 32768 + ((s*4+u)*64 + lane)*8 + j
//    value = Wh[n = u*16 + (lane&15)][k = s*32 + (lane>>4)*8 + j]
//    where Wh[n][k]: n<32 -> Wmu[k][n], else Wsg[k][n-32]
// ---------------------------------------------------------------------------
__global__ void dice_prep(const float* __restrict__ Wbb,
                          const float* __restrict__ Wmu,
                          const float* __restrict__ Wsg,
                          unsigned short* __restrict__ wpack) {
  int tid = blockIdx.x * 256 + threadIdx.x;      // 192*256 = 49152 exactly
  if (tid < 32768) {
    int w    = tid >> 13;
    int rem  = tid & 8191;
    int f    = rem >> 9;
    int lane = (rem >> 3) & 63;
    int j    = rem & 7;
    int t = f >> 2, s = f & 3;
    int k = s * 32 + (lane >> 4) * 8 + j;
    int n = w * 64 + t * 16 + (lane & 15);
    wpack[tid] = f2bf(Wbb[k * LAT + n]);
  } else {
    int i    = tid - 32768;                      // [0, 16384)
    int f    = i >> 9;                           // frag 0..31 = s*4+u
    int lane = (i >> 3) & 63;
    int j    = i & 7;
    int s = f >> 2, u = f & 3;
    int n = u * 16 + (lane & 15);
    int k = s * 32 + (lane >> 4) * 8 + j;
    float v = (n < 32) ? Wmu[k * ACT + n] : Wsg[k * ACT + (n - 32)];
    wpack[32768 + i] = f2bf(v);
  }
}

// ---------------------------------------------------------------------------
// Main kernel: 256 threads (4 waves), 64 rows per block, grid 4096.
// Wave w owns latent cols [64w, 64w+64) in the backbone (W_bb frags in regs).
// LDS = 8K (obs half) + 32K (h) = 40960 B -> up to 4 blocks/CU by LDS.
// launch_bounds min-waves kept at 2 so the allocator is NOT starved (R2's
// (256,4) forced VGPR=64 and spilled ~150 MB of scratch traffic to HBM).
// ---------------------------------------------------------------------------
__global__ __launch_bounds__(256, 2) void dice_main(
    const float* __restrict__ obs, const float* __restrict__ noise,
    const unsigned short* __restrict__ wpack,
    const float* __restrict__ b_bb, const float* __restrict__ b_mu,
    const float* __restrict__ b_sg, float* __restrict__ out) {

  __shared__ __align__(16) unsigned char s_obs[8192];   // 32 rows x 128 bf16, swizzled
  __shared__ __align__(16) unsigned char s_h[32768];    // 64 rows x 256 bf16, swizzled

  const int tid  = threadIdx.x;
  const int wave = tid >> 6, lane = tid & 63;
  const int lrow = lane & 15, lgrp = lane >> 4;
  const int blockRow0 = blockIdx.x * 64;

  // ---- W_bb fragments -> registers (coalesced 16B/lane, L2-hot) ----
  bf16x8 wf[16];
  {
    const bf16x8* wp = (const bf16x8*)wpack + wave * 1024 + lane;
#pragma unroll
    for (int f = 0; f < 16; ++f) wf[f] = wp[f * 64];
  }

  // backbone bias per owned col
  float bbias[4];
#pragma unroll
  for (int t = 0; t < 4; ++t) bbias[t] = b_bb[wave * 64 + t * 16 + lrow];

  // ---- stage obs half (32 rows) into s_obs, f32 -> bf16, swizzled ----
  auto stage_obs = [&](int half) {
    const float4* op = (const float4*)obs + (size_t)(blockRow0 + half * 32) * 32;
#pragma unroll
    for (int i = 0; i < 4; ++i) {
      int flat = i * 256 + tid;
      int m = flat >> 5, kq = flat & 31;           // m: local row, kq: float4 idx in row
      float4 v = op[m * 32 + kq];
      unsigned int lo = (unsigned int)f2bf(v.x) | ((unsigned int)f2bf(v.y) << 16);
      unsigned int hi = (unsigned int)f2bf(v.z) | ((unsigned int)f2bf(v.w) << 16);
      int byte = m * 256 + ((kq * 8) ^ ((m & 15) << 4));
      *(uint2*)(s_obs + byte) = make_uint2(lo, hi);
    }
  };

  // ---- backbone for one 16-row strip: h[m0..m0+16)[wave cols] ----
  auto backbone = [&](int st) {
    const int m0 = st * 16, mloc = (st & 1) * 16;
    bf16x8 a[4];
#pragma unroll
    for (int s = 0; s < 4; ++s) {
      int abyte = (mloc + lrow) * 256 + ((s * 64 + lgrp * 16) ^ (lrow << 4));
      a[s] = *(const bf16x8*)(s_obs + abyte);
    }
    f32x4 acc[4];
#pragma unroll
    for (int t = 0; t < 4; ++t) acc[t] = (f32x4)(0.f);
#pragma unroll
    for (int t = 0; t < 4; ++t)
#pragma unroll
      for (int s = 0; s < 4; ++s)
        acc[t] = __builtin_amdgcn_mfma_f32_16x16x32_bf16(a[s], wf[t * 4 + s], acc[t], 0, 0, 0);
    // bias + relu + bf16 -> s_h (swizzled)
#pragma unroll
    for (int t = 0; t < 4; ++t) {
      int col = wave * 64 + t * 16 + lrow;
#pragma unroll
      for (int r = 0; r < 4; ++r) {
        int row = m0 + lgrp * 4 + r;
        float v = fmaxf(acc[t][r] + bbias[t], 0.f);
        int byte = row * 512 + ((2 * col) ^ ((row & 15) << 4));
        *(unsigned short*)(s_h + byte) = f2bf(v);
      }
    }
  };

  stage_obs(0);
  __syncthreads();
  backbone(0);
  backbone(1);
  __syncthreads();
  stage_obs(1);
  __syncthreads();
  backbone(2);
  backbone(3);
  __syncthreads();

  // ---- head GEMM: rows [wave*16, wave*16+16), cols mu(0-31) | logstd(0-31) ----
  // B-fragments streamed straight from global (32 KB table, L2/L1-hot).
  const bf16x8* hb = (const bf16x8*)(wpack + 32768);
  f32x4 acc2[4];
#pragma unroll
  for (int u = 0; u < 4; ++u) acc2[u] = (f32x4)(0.f);
#pragma unroll
  for (int s = 0; s < 8; ++s) {
    int off = (s * 64 + lgrp * 16) ^ (lrow << 4);
    bf16x8 a = *(const bf16x8*)(s_h + (wave * 16 + lrow) * 512 + off);
#pragma unroll
    for (int u = 0; u < 4; ++u) {
      bf16x8 b = hb[(s * 4 + u) * 64 + lane];
      acc2[u] = __builtin_amdgcn_mfma_f32_16x16x32_bf16(a, b, acc2[u], 0, 0, 0);
    }
  }

  // ---- epilogue ----
  const float bmu0 = b_mu[lrow], bmu1 = b_mu[lrow + 16];
  const float bsg0 = b_sg[lrow], bsg1 = b_sg[lrow + 16];
  float* out_act = out;
  float* out_pre = out + (B_TOTAL * ACT);
  float* out_lp  = out + (2 * B_TOTAL * ACT);
  float* out_plp = out_lp + B_TOTAL;

  float s1v[4], s2v[4];
#pragma unroll
  for (int r = 0; r < 4; ++r) {
    int row = blockRow0 + wave * 16 + lgrp * 4 + r;
    float mu0 = fminf(fmaxf(acc2[0][r] + bmu0, -7.f), 7.f);
    float mu1 = fminf(fmaxf(acc2[1][r] + bmu1, -7.f), 7.f);
    float ls0 = fminf(fmaxf(acc2[2][r] + bsg0, -2.f), 5.f);
    float ls1 = fminf(fmaxf(acc2[3][r] + bsg1, -2.f), 5.f);
    float n0 = noise[row * ACT + lrow];
    float n1 = noise[row * ACT + lrow + 16];
    float sp0 = __expf(0.5f * ls0), sp1 = __expf(0.5f * ls1);
    float p0 = fmaf(sp0, n0, mu0), p1 = fmaf(sp1, n1, mu1);
    float a0 = ftanh(p0), a1 = ftanh(p1);
    float d0 = p0 - mu0, d1 = p1 - mu1;
    float t1 = fmaf(d0 * d0, __expf(-ls0), ls0) + fmaf(d1 * d1, __expf(-ls1), ls1);
    float t2 = __logf(1.f - a0 * a0 + 1e-6f) + __logf(1.f - a1 * a1 + 1e-6f);
    out_act[row * ACT + lrow]      = a0;
    out_act[row * ACT + lrow + 16] = a1;
    out_pre[row * ACT + lrow]      = p0;
    out_pre[row * ACT + lrow + 16] = p1;
    s1v[r] = t1;
    s2v[r] = t2;
  }
  // 16-lane butterfly: every lane in a 16-group ends with full row sums
#pragma unroll
  for (int m = 1; m < 16; m <<= 1) {
#pragma unroll
    for (int r = 0; r < 4; ++r) {
      s1v[r] += __shfl_xor(s1v[r], m, 64);
      s2v[r] += __shfl_xor(s2v[r], m, 64);
    }
  }
  if (lrow < 4) {
    int r = lrow;
    float s1 = (r == 0) ? s1v[0] : (r == 1) ? s1v[1] : (r == 2) ? s1v[2] : s1v[3];
    float s2 = (r == 0) ? s2v[0] : (r == 1) ? s2v[1] : (r == 2) ? s2v[2] : s2v[3];
    int row = blockRow0 + wave * 16 + lgrp * 4 + r;
    float plp = -0.5f * s1 - 29.406033062549525f;   // 0.5*32*log(2*pi)
    out_plp[row] = plp;
    out_lp[row]  = plp - s2;
  }
}

extern "C" void kernel_launch(void* const* d_in, const int* in_sizes, int n_in,
                              void* d_out, int out_size, void* d_ws, size_t ws_size,
                              hipStream_t stream) {
  const float* obs = (const float*)d_in[0];
  const float* noi = (const float*)d_in[1];
  const float* Wbb = (const float*)d_in[2];
  const float* bbb = (const float*)d_in[3];
  const float* Wmu = (const float*)d_in[4];
  const float* bmu = (const float*)d_in[5];
  const float* Wsg = (const float*)d_in[6];
  const float* bsg = (const float*)d_in[7];
  unsigned short* wpack = (unsigned short*)d_ws;   // needs 98304 bytes

  hipLaunchKernelGGL(dice_prep, dim3(192), dim3(256), 0, stream, Wbb, Wmu, Wsg, wpack);
  hipLaunchKernelGGL(dice_main, dim3(B_TOTAL / 64), dim3(256), 0, stream,
                     obs, noi, wpack, bbb, bmu, bsg, (float*)d_out);
}